// Round 1
// 119.606 us; speedup vs baseline: 1.0288x; 1.0288x over previous
//
#include <hip/hip_runtime.h>
#include <math.h>

// Density loss: B=8, N=2048, C=3, K=16 (includes self-distance 0).
// One wave per point. Points staged SoA in LDS (x/y/z float arrays, 24 KB).
// Per lane: 32 candidate distances in registers (4 per ds_read_b128 triple).
// Selection without sorts/compaction:
//   1) thr >= true 16th-smallest via scalar-pipe ballot bisection on the
//      64 lane-mins (uint-ordered floats; invariant count(hi) >= 16).
//   2) per-lane count/sum of qualifying (d <= thr) + 3 largest qualifying
//      in registers; total C via ballots (E[C] ~ 18, E[qcnt/lane] ~ 0.28).
//   3) sum16 = sum(qualifying) - (C-16) largest, popped by ~2 expected
//      rounds of wave-max. Lanes with qcnt >= 4 (rare) -> exact fallback.
// Kernel 2: single block reduces 2x8x2048 per-point sums -> scalar MSE.

#define NPTS 2048
#define KSEL 16
#define WAVES_PER_BLOCK 8
#define BLOCK (WAVES_PER_BLOCK * 64)        // 512
#define NGROUPS (NPTS / WAVES_PER_BLOCK)    // 256
#define NBLOCKS (2 * 8 * NGROUPS)           // 4096

__device__ __forceinline__ float wave_sum_f(float v) {
  #pragma unroll
  for (int ofs = 32; ofs >= 1; ofs >>= 1) v += __shfl_xor(v, ofs);
  return v;
}

__device__ __forceinline__ float wave_max_f(float v) {
  #pragma unroll
  for (int ofs = 32; ofs >= 1; ofs >>= 1) v = fmaxf(v, __shfl_xor(v, ofs));
  return v;
}

__global__ __launch_bounds__(BLOCK) void knn_sum16_kernel(
    const float* __restrict__ seed, const float* __restrict__ gt,
    float* __restrict__ out_sums) {
  __shared__ float xs[NPTS];
  __shared__ float ys[NPTS];
  __shared__ float zs[NPTS];

  const int bid = blockIdx.x;        // 4096 blocks
  const int t = bid >> 11;           // tensor: 0=seed 1=gt
  const int b = (bid >> 8) & 7;      // batch
  const int g = bid & 255;           // point-group within batch
  const float* base = (t == 0 ? seed : gt) + b * NPTS * 3;

  const int tid = threadIdx.x;

  // Stage SoA: thread tid handles points 4*tid..4*tid+3 (12 floats = 3 float4).
  {
    const float4* src = (const float4*)base;
    float4 f0 = src[3 * tid + 0];
    float4 f1 = src[3 * tid + 1];
    float4 f2 = src[3 * tid + 2];
    *(float4*)&xs[4 * tid] = make_float4(f0.x, f0.w, f1.z, f2.y);
    *(float4*)&ys[4 * tid] = make_float4(f0.y, f1.x, f1.w, f2.z);
    *(float4*)&zs[4 * tid] = make_float4(f0.z, f1.y, f2.x, f2.w);
  }
  __syncthreads();

  const int wave = tid >> 6;
  const int lane = tid & 63;
  const int i = g * WAVES_PER_BLOCK + wave;  // point index within batch
  const float pix = xs[i], piy = ys[i], piz = zs[i];

  // 32 distances per lane: candidate index = 4*lane + j + 256*m.
  float d[32];
  float lma = INFINITY, lmb = INFINITY, lmc = INFINITY, lmd = INFINITY;
  #pragma unroll
  for (int m = 0; m < 8; ++m) {
    const int o = (lane << 2) + (m << 8);
    float4 cx = *(const float4*)&xs[o];
    float4 cy = *(const float4*)&ys[o];
    float4 cz = *(const float4*)&zs[o];
    float dx, dy, dz, dd;
    dx = pix - cx.x; dy = piy - cy.x; dz = piz - cz.x;
    dd = fmaf(dz, dz, fmaf(dy, dy, dx * dx));
    d[(m << 2) + 0] = dd; lma = fminf(lma, dd);
    dx = pix - cx.y; dy = piy - cy.y; dz = piz - cz.y;
    dd = fmaf(dz, dz, fmaf(dy, dy, dx * dx));
    d[(m << 2) + 1] = dd; lmb = fminf(lmb, dd);
    dx = pix - cx.z; dy = piy - cy.z; dz = piz - cz.z;
    dd = fmaf(dz, dz, fmaf(dy, dy, dx * dx));
    d[(m << 2) + 2] = dd; lmc = fminf(lmc, dd);
    dx = pix - cx.w; dy = piy - cy.w; dz = piz - cz.w;
    dd = fmaf(dz, dz, fmaf(dy, dy, dx * dx));
    d[(m << 2) + 3] = dd; lmd = fminf(lmd, dd);
  }
  const unsigned lmu =
      __float_as_uint(fminf(fminf(lma, lmb), fminf(lmc, lmd)));

  // Threshold: bisect smallest t (within 2^11 ulp) with >=16 lane-mins <= t.
  // Nonneg floats are uint-order-isomorphic. Invariant: count(hi) >= 16, so
  // thr >= 16th-smallest lane-min >= true 16th-smallest distance. Scalar pipe.
  unsigned lo = 0u, hi = 0x7F800000u;  // [0, +inf]
  #pragma unroll
  for (int r = 0; r < 20; ++r) {
    unsigned mid = (lo + hi) >> 1;
    int cnt = __popcll(__ballot(lmu <= mid));
    bool ge = cnt >= KSEL;
    hi = ge ? mid : hi;
    lo = ge ? lo : mid;
  }
  const float thr = __uint_as_float(hi);

  // Per-lane: count & sum of qualifying (d <= thr) + 3 largest qualifying.
  float g0 = -INFINITY, g1 = -INFINITY, g2 = -INFINITY;
  float sq = 0.f;
  int qc = 0;
  #pragma unroll
  for (int m = 0; m < 32; ++m) {
    const float dd = d[m];
    const bool q = dd <= thr;
    const float qd = q ? dd : -INFINITY;
    sq += fmaxf(qd, 0.0f);  // d >= 0, so adds qualifying d else 0
    qc += q ? 1 : 0;
    const bool c0 = qd > g0;
    const bool c1 = qd > g1;
    const float ng2 = c1 ? g1 : fmaxf(g2, qd);
    const float ng1 = c0 ? g0 : fmaxf(g1, qd);
    g2 = ng2;
    g1 = ng1;
    g0 = fmaxf(g0, qd);
  }

  const unsigned long long anyb4 = __ballot(qc >= 4);
  float sum16;
  if (anyb4 == 0ull) {
    // All qualifying values are materialized in {g0,g1,g2} across the wave.
    const int C = __popcll(__ballot(qc >= 1)) + __popcll(__ballot(qc >= 2)) +
                  __popcll(__ballot(qc >= 3));  // C >= 16 guaranteed by thr
    const float S = wave_sum_f(sq);
    int extras = C - KSEL;  // E[extras] ~ 2
    float h0 = g0, h1 = g1, h2 = g2;
    float sub = 0.f;
    while (extras > 0) {
      const float M = wave_max_f(h0);  // finite: >16 values remain
      const unsigned long long sel = __ballot(h0 == M);
      const int leader = (int)__ffsll(sel) - 1;
      if (lane == leader) { h0 = h1; h1 = h2; h2 = -INFINITY; }
      sub += M;
      --extras;
    }
    sum16 = S - sub;
  } else {
    // Exact fallback (rare, ~1% of waves): 16 extraction rounds over d[].
    unsigned consumed = 0;
    float s = 0.f;
    for (int r = 0; r < KSEL; ++r) {
      float bv = INFINITY;
      int bi = 0;
      #pragma unroll
      for (int m = 0; m < 32; ++m) {
        bool ok = (((consumed >> m) & 1u) == 0u) && (d[m] < bv);
        bv = ok ? d[m] : bv;
        bi = ok ? m : bi;
      }
      int bl = lane;
      #pragma unroll
      for (int ofs = 32; ofs >= 1; ofs >>= 1) {
        float ov = __shfl_xor(bv, ofs);
        int ol = __shfl_xor(bl, ofs);
        bool take = (ov < bv) || (ov == bv && ol < bl);
        bv = take ? ov : bv;
        bl = take ? ol : bl;
      }
      s += bv;
      if (lane == bl) consumed |= (1u << bi);
    }
    sum16 = s;
  }

  if (lane == 0) out_sums[bid * WAVES_PER_BLOCK + wave] = sum16;
}

__global__ __launch_bounds__(1024) void final_reduce_kernel(
    const float* __restrict__ sums, float* __restrict__ out) {
  __shared__ float partial[16];
  const int tid = threadIdx.x;
  const int wave = tid >> 6;
  const int lane = tid & 63;
  // wave w reduces segment (t,b) = w: 2048 per-point sum16 values.
  float s = 0.f;
  #pragma unroll
  for (int m = 0; m < 32; ++m) s += sums[wave * 2048 + lane + (m << 6)];
  #pragma unroll
  for (int ofs = 32; ofs >= 1; ofs >>= 1) s += __shfl_xor(s, ofs);
  if (lane == 0) partial[wave] = s;
  __syncthreads();
  if (tid == 0) {
    const float scale = 1.f / (2048.f * 16.f);  // mean over points, mean over k
    float acc = 0.f;
    #pragma unroll
    for (int bb = 0; bb < 8; ++bb) {
      float diff = (partial[bb] - partial[8 + bb]) * scale;
      acc += diff * diff;
    }
    out[0] = acc * 0.125f;
  }
}

extern "C" void kernel_launch(void* const* d_in, const int* in_sizes, int n_in,
                              void* d_out, int out_size, void* d_ws, size_t ws_size,
                              hipStream_t stream) {
  const float* seed = (const float*)d_in[0];
  const float* gt = (const float*)d_in[1];
  float* out = (float*)d_out;
  float* ws = (float*)d_ws;  // 32768 floats = 128 KB

  knn_sum16_kernel<<<NBLOCKS, BLOCK, 0, stream>>>(seed, gt, ws);
  final_reduce_kernel<<<1, 1024, 0, stream>>>(ws, out);
}

// Round 2
// 95.450 us; speedup vs baseline: 1.2891x; 1.2531x over previous
//
#include <hip/hip_runtime.h>
#include <math.h>

// Density loss: B=8, N=2048, C=3, K=16 (includes self-distance 0).
// One wave per TWO query points (Q=2). Points staged SoA in LDS.
// Per lane: 4 candidates x 8 groups x 2 queries; only per-group-of-4 mins
// gm[8] are kept per query (no d[32] in registers).
// Selection per query:
//   1) thr >= true d16 via interleaved ballot bisection on lane-mins.
//   2) qualifying groups (gm <= thr, E~17) compacted to LDS ids; each active
//      lane recomputes its group's 4 distances (bitwise identical fmaf).
//   3) qualifying values (C in [16,64]) compacted, 1/lane; exact 16th-smallest
//      t* via 32-round 1-ballot-per-round bit bisection;
//      sum16 = sum(v < t*) + (16 - nlo) * t*.  All trip counts fixed.
// Fallback (scratch overflow, ~never): exact 16-round extraction with
// distance recompute from LDS.
// Kernel 2: single block reduces 2x8x2048 per-point sums -> scalar MSE.

#define NPTS 2048
#define KSEL 16
#define WAVES_PER_BLOCK 8
#define BLOCK (WAVES_PER_BLOCK * 64)         // 512
#define PTS_PER_BLOCK (WAVES_PER_BLOCK * 2)  // 16
#define NGROUPS (NPTS / PTS_PER_BLOCK)       // 128
#define NBLOCKS (2 * 8 * NGROUPS)            // 2048

__device__ __forceinline__ float wave_sum_f(float v) {
  #pragma unroll
  for (int ofs = 32; ofs >= 1; ofs >>= 1) v += __shfl_xor(v, ofs);
  return v;
}

__device__ __forceinline__ float dist2(float px, float py, float pz,
                                       float cx, float cy, float cz) {
  float dx = px - cx, dy = py - cy, dz = pz - cz;
  return fmaf(dz, dz, fmaf(dy, dy, dx * dx));
}

// Per-query selection. gm: 8 group-mins (registers). scrI/scrV: this wave's
// private 64-entry LDS scratch. Returns exact sum of 16 smallest distances.
__device__ __forceinline__ float select_sum16(
    const float (&gm)[8], float thr, float px, float py, float pz, int lane,
    const float* xs, const float* ys, const float* zs, int* scrI,
    float* scrV) {
  // --- group qualification + compaction of group ids ---
  int qg = 0;
  #pragma unroll
  for (int m = 0; m < 8; ++m) qg += (gm[m] <= thr) ? 1 : 0;
  int incl = qg;
  #pragma unroll
  for (int ofs = 1; ofs < 64; ofs <<= 1) {
    int y = __shfl_up(incl, ofs);
    if (lane >= ofs) incl += y;
  }
  const int tot = __shfl(incl, 63);
  bool ok = (tot <= 64);
  if (ok) {
    int pos = incl - qg;
    #pragma unroll
    for (int m = 0; m < 8; ++m) {
      if (gm[m] <= thr) {
        scrI[pos] = (lane << 3) | m;
        ++pos;
      }
    }
  }

  // --- redistribute: one qualifying group per active lane, recompute 4 d ---
  float d0 = INFINITY, d1 = INFINITY, d2 = INFINITY, d3 = INFINITY;
  if (ok && lane < tot) {
    const int id = scrI[lane];
    const int o = ((id >> 3) << 2) + ((id & 7) << 8);
    float4 cx4 = *(const float4*)&xs[o];
    float4 cy4 = *(const float4*)&ys[o];
    float4 cz4 = *(const float4*)&zs[o];
    d0 = dist2(px, py, pz, cx4.x, cy4.x, cz4.x);
    d1 = dist2(px, py, pz, cx4.y, cy4.y, cz4.y);
    d2 = dist2(px, py, pz, cx4.z, cy4.z, cz4.z);
    d3 = dist2(px, py, pz, cx4.w, cy4.w, cz4.w);
  }

  // --- compact qualifying values, one per lane ---
  const int qn = ((d0 <= thr) ? 1 : 0) + ((d1 <= thr) ? 1 : 0) +
                 ((d2 <= thr) ? 1 : 0) + ((d3 <= thr) ? 1 : 0);
  int incl2 = qn;
  #pragma unroll
  for (int ofs = 1; ofs < 64; ofs <<= 1) {
    int y = __shfl_up(incl2, ofs);
    if (lane >= ofs) incl2 += y;
  }
  const int C = __shfl(incl2, 63);  // C >= 16 guaranteed (thr >= d16)
  ok = ok && (C <= 64);

  float res;
  if (ok) {
    int vpos = incl2 - qn;
    if (d0 <= thr) scrV[vpos++] = d0;
    if (d1 <= thr) scrV[vpos++] = d1;
    if (d2 <= thr) scrV[vpos++] = d2;
    if (d3 <= thr) scrV[vpos++] = d3;
    const float v = (lane < C) ? scrV[lane] : INFINITY;

    // Exact 16th-smallest via bit bisection on w = bits(v)+1 (handles v==0).
    // Invariants: count(w <= hi) >= 16, count(w <= lo) < 16. 32 rounds pin
    // hi = lo+1 exactly.
    const unsigned wv = __float_as_uint(v) + 1u;
    unsigned lo = 0u, hi = 0x7F800001u;
    #pragma unroll 1
    for (int r = 0; r < 32; ++r) {
      const unsigned mid = (lo + hi) >> 1;
      const int c = __popcll(__ballot(wv <= mid));
      const bool ge = (c >= KSEL);
      hi = ge ? mid : hi;
      lo = ge ? lo : mid;
    }
    const float tstar = __uint_as_float(hi - 1u);
    const int nlo = __popcll(__ballot(wv <= lo));  // count(v < t*) < 16
    float contrib = (wv <= lo) ? v : 0.f;
    contrib = wave_sum_f(contrib);
    res = contrib + (float)(KSEL - nlo) * tstar;
  } else {
    // Exact fallback (~never): 16 extraction rounds, recompute from LDS.
    float s = 0.f;
    unsigned consumed = 0u;
    #pragma unroll 1
    for (int r = 0; r < KSEL; ++r) {
      float bv = INFINITY;
      int bi = 0;
      #pragma unroll
      for (int m = 0; m < 8; ++m) {
        const int o = (lane << 2) + (m << 8);
        float4 cx4 = *(const float4*)&xs[o];
        float4 cy4 = *(const float4*)&ys[o];
        float4 cz4 = *(const float4*)&zs[o];
        float dd;
        bool okb;
        dd = dist2(px, py, pz, cx4.x, cy4.x, cz4.x);
        okb = (((consumed >> ((m << 2) + 0)) & 1u) == 0u) && (dd < bv);
        bv = okb ? dd : bv; bi = okb ? ((m << 2) + 0) : bi;
        dd = dist2(px, py, pz, cx4.y, cy4.y, cz4.y);
        okb = (((consumed >> ((m << 2) + 1)) & 1u) == 0u) && (dd < bv);
        bv = okb ? dd : bv; bi = okb ? ((m << 2) + 1) : bi;
        dd = dist2(px, py, pz, cx4.z, cy4.z, cz4.z);
        okb = (((consumed >> ((m << 2) + 2)) & 1u) == 0u) && (dd < bv);
        bv = okb ? dd : bv; bi = okb ? ((m << 2) + 2) : bi;
        dd = dist2(px, py, pz, cx4.w, cy4.w, cz4.w);
        okb = (((consumed >> ((m << 2) + 3)) & 1u) == 0u) && (dd < bv);
        bv = okb ? dd : bv; bi = okb ? ((m << 2) + 3) : bi;
      }
      int bl = lane;
      #pragma unroll
      for (int ofs = 32; ofs >= 1; ofs >>= 1) {
        float ov = __shfl_xor(bv, ofs);
        int ol = __shfl_xor(bl, ofs);
        bool take = (ov < bv) || (ov == bv && ol < bl);
        bv = take ? ov : bv;
        bl = take ? ol : bl;
      }
      s += bv;
      if (lane == bl) consumed |= (1u << bi);
    }
    res = s;
  }
  return res;
}

__global__ __launch_bounds__(BLOCK) void knn_sum16_kernel(
    const float* __restrict__ seed, const float* __restrict__ gt,
    float* __restrict__ out_sums) {
  __shared__ float xs[NPTS];
  __shared__ float ys[NPTS];
  __shared__ float zs[NPTS];
  __shared__ int scrI[WAVES_PER_BLOCK][2][64];
  __shared__ float scrV[WAVES_PER_BLOCK][2][64];

  const int bid = blockIdx.x;        // 2048 blocks
  const int t = bid >> 10;           // tensor: 0=seed 1=gt
  const int b = (bid >> 7) & 7;      // batch
  const int g = bid & 127;           // point-group within batch
  const float* base = (t == 0 ? seed : gt) + b * NPTS * 3;

  const int tid = threadIdx.x;

  // Stage SoA: thread tid handles points 4*tid..4*tid+3 (12 floats).
  {
    const float4* src = (const float4*)base;
    float4 f0 = src[3 * tid + 0];
    float4 f1 = src[3 * tid + 1];
    float4 f2 = src[3 * tid + 2];
    *(float4*)&xs[4 * tid] = make_float4(f0.x, f0.w, f1.z, f2.y);
    *(float4*)&ys[4 * tid] = make_float4(f0.y, f1.x, f1.w, f2.z);
    *(float4*)&zs[4 * tid] = make_float4(f0.z, f1.y, f2.x, f2.w);
  }
  __syncthreads();

  const int wave = tid >> 6;
  const int lane = tid & 63;
  const int iA = g * PTS_PER_BLOCK + wave * 2;  // query point A
  const int iB = iA + 1;                        // query point B
  const float pax = xs[iA], pay = ys[iA], paz = zs[iA];
  const float pbx = xs[iB], pby = ys[iB], pbz = zs[iB];

  // Distance pass: candidate index = 4*lane + j + 256*m. Keep group mins.
  float gmA[8], gmB[8];
  #pragma unroll
  for (int m = 0; m < 8; ++m) {
    const int o = (lane << 2) + (m << 8);
    float4 cx4 = *(const float4*)&xs[o];
    float4 cy4 = *(const float4*)&ys[o];
    float4 cz4 = *(const float4*)&zs[o];
    float a0 = dist2(pax, pay, paz, cx4.x, cy4.x, cz4.x);
    float a1 = dist2(pax, pay, paz, cx4.y, cy4.y, cz4.y);
    float a2 = dist2(pax, pay, paz, cx4.z, cy4.z, cz4.z);
    float a3 = dist2(pax, pay, paz, cx4.w, cy4.w, cz4.w);
    gmA[m] = fminf(fminf(a0, a1), fminf(a2, a3));
    float b0 = dist2(pbx, pby, pbz, cx4.x, cy4.x, cz4.x);
    float b1 = dist2(pbx, pby, pbz, cx4.y, cy4.y, cz4.y);
    float b2 = dist2(pbx, pby, pbz, cx4.z, cy4.z, cz4.z);
    float b3 = dist2(pbx, pby, pbz, cx4.w, cy4.w, cz4.w);
    gmB[m] = fminf(fminf(b0, b1), fminf(b2, b3));
  }
  float lminA = gmA[0], lminB = gmB[0];
  #pragma unroll
  for (int m = 1; m < 8; ++m) {
    lminA = fminf(lminA, gmA[m]);
    lminB = fminf(lminB, gmB[m]);
  }

  // Interleaved threshold bisection (16 rounds): thr >= 16th-smallest
  // lane-min >= true d16; looseness <= ~0.3% in value (C inflation ~0).
  const unsigned uA = __float_as_uint(lminA);
  const unsigned uB = __float_as_uint(lminB);
  unsigned loA = 0u, hiA = 0x7F800000u, loB = 0u, hiB = 0x7F800000u;
  #pragma unroll 1
  for (int r = 0; r < 16; ++r) {
    const unsigned midA = (loA + hiA) >> 1;
    const unsigned midB = (loB + hiB) >> 1;
    const int cA = __popcll(__ballot(uA <= midA));
    const int cB = __popcll(__ballot(uB <= midB));
    const bool gA = cA >= KSEL;
    const bool gB = cB >= KSEL;
    hiA = gA ? midA : hiA;
    loA = gA ? loA : midA;
    hiB = gB ? midB : hiB;
    loB = gB ? loB : midB;
  }
  const float thrA = __uint_as_float(hiA);
  const float thrB = __uint_as_float(hiB);

  const float sumA =
      select_sum16(gmA, thrA, pax, pay, paz, lane, xs, ys, zs,
                   &scrI[wave][0][0], &scrV[wave][0][0]);
  const float sumB =
      select_sum16(gmB, thrB, pbx, pby, pbz, lane, xs, ys, zs,
                   &scrI[wave][1][0], &scrV[wave][1][0]);

  if (lane == 0) {
    out_sums[bid * PTS_PER_BLOCK + wave * 2 + 0] = sumA;
    out_sums[bid * PTS_PER_BLOCK + wave * 2 + 1] = sumB;
  }
}

__global__ __launch_bounds__(1024) void final_reduce_kernel(
    const float* __restrict__ sums, float* __restrict__ out) {
  __shared__ float partial[16];
  const int tid = threadIdx.x;
  const int wave = tid >> 6;
  const int lane = tid & 63;
  // wave w reduces segment (t,b) = w: 2048 per-point sum16 values.
  float s = 0.f;
  #pragma unroll
  for (int m = 0; m < 32; ++m) s += sums[wave * 2048 + lane + (m << 6)];
  #pragma unroll
  for (int ofs = 32; ofs >= 1; ofs >>= 1) s += __shfl_xor(s, ofs);
  if (lane == 0) partial[wave] = s;
  __syncthreads();
  if (tid == 0) {
    const float scale = 1.f / (2048.f * 16.f);  // mean over points, mean over k
    float acc = 0.f;
    #pragma unroll
    for (int bb = 0; bb < 8; ++bb) {
      float diff = (partial[bb] - partial[8 + bb]) * scale;
      acc += diff * diff;
    }
    out[0] = acc * 0.125f;
  }
}

extern "C" void kernel_launch(void* const* d_in, const int* in_sizes, int n_in,
                              void* d_out, int out_size, void* d_ws, size_t ws_size,
                              hipStream_t stream) {
  const float* seed = (const float*)d_in[0];
  const float* gt = (const float*)d_in[1];
  float* out = (float*)d_out;
  float* ws = (float*)d_ws;  // 32768 floats = 128 KB

  knn_sum16_kernel<<<NBLOCKS, BLOCK, 0, stream>>>(seed, gt, ws);
  final_reduce_kernel<<<1, 1024, 0, stream>>>(ws, out);
}